// Round 1
// baseline (597.759 us; speedup 1.0000x reference)
//
#include <hip/hip_runtime.h>
#include <hip/hip_bf16.h>

#define T_LEN 1024
#define NT 128  // tagset size

// Raw barrier: drain LDS ops (write visibility) but NOT vmcnt, so global
// prefetch loads stay in flight across the barrier (default __syncthreads
// drains vmcnt(0) and would serialize the feats prefetch every step).
__device__ __forceinline__ void bar_lds() {
  asm volatile("s_waitcnt lgkmcnt(0)" ::: "memory");
  __builtin_amdgcn_s_barrier();
}

__global__ __launch_bounds__(256) void crf_forward_kernel(
    const float* __restrict__ feats, const float* __restrict__ trans,
    const float* __restrict__ start, const float* __restrict__ stop,
    float* __restrict__ fwd_out) {
  const int b = blockIdx.x;
  const int tid = (int)threadIdx.x;
  const int lane = tid & 63;
  const int w = tid >> 6;   // wave 0..3
  const int jg = tid & 31;  // j-quad index (j = 4*jg + jj)
  const int ig = tid >> 5;  // 0..7, i-block of 16
  const int j = tid & 127;  // phase-B tag index

  alignas(16) __shared__ float pbuf[2][NT];
  alignas(16) __shared__ float part[4 * NT];
  __shared__ float wred[4];

  const float* fb = feats + (size_t)b * T_LEN * NT;

  // E fragment in registers: E[jj][k] = exp(trans[4*jg+jj][16*ig+k])
  float E[4][16];
#pragma unroll
  for (int jj = 0; jj < 4; ++jj) {
#pragma unroll
    for (int kk = 0; kk < 4; ++kk) {
      float4 tq = *reinterpret_cast<const float4*>(
          &trans[(4 * jg + jj) * NT + 16 * ig + 4 * kk]);
      E[jj][4 * kk + 0] = __expf(tq.x);
      E[jj][4 * kk + 1] = __expf(tq.y);
      E[jj][4 * kk + 2] = __expf(tq.z);
      E[jj][4 * kk + 3] = __expf(tq.w);
    }
  }

  // init: p0[j] = exp(start[j] + feats[b,0,j]), C = 0
  {
    float fv0 = start[j] + fb[j];
    if (tid < NT) pbuf[0][j] = __expf(fv0);
  }
  float C = 0.f;

  // prefetch ring: feats for steps 1..4 (depth-4 hides HBM latency)
  float fring[4], f0ring[4];
#pragma unroll
  for (int k = 0; k < 4; ++k) {
    fring[k] = fb[(1 + k) * NT + j];
    f0ring[k] = fb[(1 + k) * NT];
  }
  bar_lds();

  int cur = 0;
  for (int tt = 0; tt < 256; ++tt) {
#pragma unroll
    for (int k = 0; k < 4; ++k) {
      const int t = 1 + tt * 4 + k;
      if (t <= 1023) {
        // ---- phase A: partial GEMV  s_part[jj] = sum_{i in my 16} p[i]*E[jj][i]
        float a0 = 0.f, a1 = 0.f, a2 = 0.f, a3 = 0.f;
        const float* pb = &pbuf[cur][ig * 16];
#pragma unroll
        for (int kk = 0; kk < 4; ++kk) {
          float4 p4 = *reinterpret_cast<const float4*>(pb + 4 * kk);
          a0 = fmaf(p4.x, E[0][4 * kk + 0], a0);
          a0 = fmaf(p4.y, E[0][4 * kk + 1], a0);
          a0 = fmaf(p4.z, E[0][4 * kk + 2], a0);
          a0 = fmaf(p4.w, E[0][4 * kk + 3], a0);
          a1 = fmaf(p4.x, E[1][4 * kk + 0], a1);
          a1 = fmaf(p4.y, E[1][4 * kk + 1], a1);
          a1 = fmaf(p4.z, E[1][4 * kk + 2], a1);
          a1 = fmaf(p4.w, E[1][4 * kk + 3], a1);
          a2 = fmaf(p4.x, E[2][4 * kk + 0], a2);
          a2 = fmaf(p4.y, E[2][4 * kk + 1], a2);
          a2 = fmaf(p4.z, E[2][4 * kk + 2], a2);
          a2 = fmaf(p4.w, E[2][4 * kk + 3], a2);
          a3 = fmaf(p4.x, E[3][4 * kk + 0], a3);
          a3 = fmaf(p4.y, E[3][4 * kk + 1], a3);
          a3 = fmaf(p4.z, E[3][4 * kk + 2], a3);
          a3 = fmaf(p4.w, E[3][4 * kk + 3], a3);
        }
        // combine ig pairs within wave (lanes l and l^32 share jg)
        a0 += __shfl_xor(a0, 32);
        a1 += __shfl_xor(a1, 32);
        a2 += __shfl_xor(a2, 32);
        a3 += __shfl_xor(a3, 32);
        if (lane < 32) {  // lane == jg here
          float4 v = make_float4(a0, a1, a2, a3);
          *reinterpret_cast<float4*>(&part[w * NT + 4 * jg]) = v;
        }
        bar_lds();

        // ---- phase B: s, s0, normalize, write p'
        float eterm = __expf(fring[k] - f0ring[k]);  // independent of part
        float s = (part[0 * NT + j] + part[1 * NT + j]) +
                  (part[2 * NT + j] + part[3 * NT + j]);
        float s0 = (part[0 * NT + 0] + part[1 * NT + 0]) +
                   (part[2 * NT + 0] + part[3 * NT + 0]);
        float r = __builtin_amdgcn_rcpf(s0);
        float pnew = s * r * eterm;
        if (tid < NT) pbuf[cur ^ 1][j] = pnew;
        C += __logf(s0) + f0ring[k];
        const int tn = t + 4;
        if (tn <= 1023) {
          fring[k] = fb[tn * NT + j];
          f0ring[k] = fb[tn * NT];
        }
        bar_lds();
        cur ^= 1;
      }
    }
  }

  // final: fwd = C + log( sum_j p[j] * exp(stop[j]) ); final p is in pbuf[1]
  float val = (tid < NT) ? pbuf[1][j] * __expf(stop[j]) : 0.f;
#pragma unroll
  for (int off = 1; off <= 32; off <<= 1) val += __shfl_xor(val, off);
  if (lane == 0) wred[w] = val;
  bar_lds();
  if (tid == 0) {
    float tot = (wred[0] + wred[1]) + (wred[2] + wred[3]);
    fwd_out[b] = C + __logf(tot);
  }
}

__global__ __launch_bounds__(256) void crf_gold_kernel(
    const float* __restrict__ feats, const float* __restrict__ trans,
    const float* __restrict__ start, const float* __restrict__ stop,
    const int* __restrict__ tags, const float* __restrict__ fwd,
    float* __restrict__ diff) {
  const int b = blockIdx.x;
  const int tid = (int)threadIdx.x;
  const int lane = tid & 63;
  const int w = tid >> 6;
  const int* tg = tags + b * T_LEN;
  const float* fb = feats + (size_t)b * T_LEN * NT;

  float acc = 0.f;
  for (int s = tid; s < T_LEN; s += 256) {
    int cu = tg[s];
    acc += fb[s * NT + cu];
    if (s > 0) acc += trans[cu * NT + tg[s - 1]];
  }
#pragma unroll
  for (int off = 1; off <= 32; off <<= 1) acc += __shfl_xor(acc, off);
  __shared__ float wr[4];
  if (lane == 0) wr[w] = acc;
  __syncthreads();
  if (tid == 0) {
    float gold = (wr[0] + wr[1]) + (wr[2] + wr[3]) + start[tg[0]] +
                 stop[tg[T_LEN - 1]];
    diff[b] = fwd[b] - gold;
  }
}

__global__ __launch_bounds__(128) void crf_final_kernel(
    const float* __restrict__ diff, float* __restrict__ out) {
  const int tid = (int)threadIdx.x;
  const int lane = tid & 63;
  const int w = tid >> 6;
  float v = diff[tid];
#pragma unroll
  for (int off = 1; off <= 32; off <<= 1) v += __shfl_xor(v, off);
  __shared__ float wr[2];
  if (lane == 0) wr[w] = v;
  __syncthreads();
  if (tid == 0) out[0] = (wr[0] + wr[1]) * (1.0f / 128.0f);
}

extern "C" void kernel_launch(void* const* d_in, const int* in_sizes, int n_in,
                              void* d_out, int out_size, void* d_ws,
                              size_t ws_size, hipStream_t stream) {
  const float* feats = (const float*)d_in[0];
  const float* trans = (const float*)d_in[1];
  const float* start = (const float*)d_in[2];
  const float* stop = (const float*)d_in[3];
  const int* tags = (const int*)d_in[4];
  // d_in[5] = mask: all-true for this problem; ignored.
  float* ws = (float*)d_ws;
  float* fwd = ws;          // 128 floats
  float* diff = ws + 128;   // 128 floats
  float* out = (float*)d_out;

  crf_forward_kernel<<<128, 256, 0, stream>>>(feats, trans, start, stop, fwd);
  crf_gold_kernel<<<128, 256, 0, stream>>>(feats, trans, start, stop, tags, fwd,
                                           diff);
  crf_final_kernel<<<1, 128, 0, stream>>>(diff, out);
}